// Round 1
// baseline (2617.537 us; speedup 1.0000x reference)
//
#include <hip/hip_runtime.h>
#include <stdint.h>
#include <math.h>

#define K_CODES 4096
#define DIM 128
#define N_FLAT 32768      // 32 * 32 * 32
#define HW 1024           // 32*32 spatial per batch

// output offsets (in floats), concat order: quantized_st, loss, perplexity, encodings, indices
#define OFF_Q    0
#define OFF_LOSS 4194304
#define OFF_PERP 4194305
#define OFF_ENC  4194306
#define OFF_IDX  138412034

// workspace offsets (bytes)
#define WS_PACKED 0                       // 32768 * 8 = 262144
#define WS_COUNTS 262144                  // 4096 * 4 = 16384
#define WS_SUMSQ  278528                  // 4 bytes
#define WS_WSQ    278544                  // 4096 * 4

// ---------------- K1: w_sq[k] = sum_d w[k][d]^2 ----------------
__global__ __launch_bounds__(64) void wsq_kernel(const float* __restrict__ w,
                                                 float* __restrict__ wsq) {
    int k = blockIdx.x;
    int lane = threadIdx.x;
    float a = w[k * DIM + lane];
    float b = w[k * DIM + lane + 64];
    float s = a * a + b * b;
    #pragma unroll
    for (int o = 32; o > 0; o >>= 1) s += __shfl_down(s, o, 64);
    if (lane == 0) wsq[k] = s;
}

// ---------------- K2: distances + split-K argmin (+ zero-fill encodings) ----
// grid: (128 n-tiles, 8 k-chunks), block 256. Each thread: one n, 512 codes.
__global__ __launch_bounds__(256, 2) void dist_argmin(
    const float* __restrict__ x, const float* __restrict__ w,
    const float* __restrict__ wsq, unsigned long long* __restrict__ packed,
    float* __restrict__ enc)
{
    const int n = blockIdx.x * 256 + threadIdx.x;
    const int kbase = blockIdx.y * 512;
    const int b = n >> 10;
    const int hw = n & 1023;
    const float* xb = x + (size_t)b * (DIM * HW) + hw;

    // load this thread's x vector (coalesced across lanes: consecutive hw)
    float xr[DIM];
    #pragma unroll
    for (int d = 0; d < DIM; ++d) xr[d] = xb[d * HW];

    float x_sq = 0.f;
    #pragma unroll
    for (int d = 0; d < DIM; ++d) x_sq = fmaf(xr[d], xr[d], x_sq);

    // zero-fill this thread's slice of the one-hot encodings output
    // (8-byte aligned; OFF_ENC*4 is only 8-aligned so use float2)
    {
        float2* ep = (float2*)(enc + (size_t)n * K_CODES + kbase);
        float2 z2; z2.x = 0.f; z2.y = 0.f;
        #pragma unroll 8
        for (int i = 0; i < 256; ++i) ep[i] = z2;
    }

    float best = 3.4e38f;
    int bestk = kbase;

    for (int k = kbase; k < kbase + 512; k += 2) {
        const float4* w0 = (const float4*)(w + (size_t)k * DIM);
        const float4* w1 = (const float4*)(w + (size_t)(k + 1) * DIM);
        float dot0 = 0.f, dot1 = 0.f;
        #pragma unroll
        for (int dq = 0; dq < DIM / 4; ++dq) {
            float4 a = w0[dq];
            float4 c = w1[dq];
            dot0 = fmaf(xr[4*dq+0], a.x, dot0);
            dot0 = fmaf(xr[4*dq+1], a.y, dot0);
            dot0 = fmaf(xr[4*dq+2], a.z, dot0);
            dot0 = fmaf(xr[4*dq+3], a.w, dot0);
            dot1 = fmaf(xr[4*dq+0], c.x, dot1);
            dot1 = fmaf(xr[4*dq+1], c.y, dot1);
            dot1 = fmaf(xr[4*dq+2], c.z, dot1);
            dot1 = fmaf(xr[4*dq+3], c.w, dot1);
        }
        // mirror reference association: ((x_sq - 2xy) + w_sq) + 1e-8
        float d0 = x_sq - 2.0f * dot0; d0 += wsq[k];     d0 += 1e-8f;
        float d1 = x_sq - 2.0f * dot1; d1 += wsq[k + 1]; d1 += 1e-8f;
        if (d0 < best) { best = d0; bestk = k; }
        if (d1 < best) { best = d1; bestk = k + 1; }
    }

    // order-preserving float->uint map (dist >= 0 here, but handle sign anyway)
    unsigned u = __float_as_uint(best);
    u = (u & 0x80000000u) ? ~u : (u | 0x80000000u);
    unsigned long long p = ((unsigned long long)u << 32) | (unsigned)bestk;
    atomicMin(&packed[n], p);
}

// ---------------- K3: combine -> indices, one-hot 1.0, counts ---------------
__global__ __launch_bounds__(256) void combine(
    const unsigned long long* __restrict__ packed,
    float* __restrict__ idxf, float* __restrict__ enc,
    float* __restrict__ counts)
{
    int n = blockIdx.x * 256 + threadIdx.x;
    unsigned k = (unsigned)(packed[n] & 0xFFFFFFFFu);
    idxf[n] = (float)k;
    enc[(size_t)n * K_CODES + k] = 1.0f;
    atomicAdd(&counts[k], 1.0f);
}

// ---------------- K4: gather codebook -> quantized_st (NCHW) + loss sum -----
__global__ __launch_bounds__(256) void quantize_loss(
    const float* __restrict__ x, const float* __restrict__ w,
    const float* __restrict__ idxf, float* __restrict__ outq,
    float* __restrict__ sumsq)
{
    int tid = blockIdx.x * 256 + threadIdx.x;   // NCHW element index
    int hw = tid & 1023;
    int c  = (tid >> 10) & 127;
    int b  = tid >> 17;
    int n  = (b << 10) | hw;
    int k  = (int)idxf[n];
    float q  = w[k * DIM + c];
    float xv = x[tid];
    float diff = q - xv;                 // fl(q - x), matches reference rounding
    outq[tid] = xv + diff;               // quantized_st = x + (q - x)
    float s = diff * diff;
    #pragma unroll
    for (int o = 32; o > 0; o >>= 1) s += __shfl_down(s, o, 64);
    __shared__ float ls[4];
    if ((threadIdx.x & 63) == 0) ls[threadIdx.x >> 6] = s;
    __syncthreads();
    if (threadIdx.x == 0) atomicAdd(sumsq, ls[0] + ls[1] + ls[2] + ls[3]);
}

// ---------------- K5: loss + perplexity ------------------------------------
__global__ __launch_bounds__(256) void finalize(
    const float* __restrict__ counts, const float* __restrict__ sumsq,
    float* __restrict__ out)
{
    __shared__ float sh[256];
    float h = 0.f;
    for (int k = threadIdx.x; k < K_CODES; k += 256) {
        float p = counts[k] * (1.0f / N_FLAT);
        h += p * logf(p + 1e-10f);
    }
    sh[threadIdx.x] = h;
    __syncthreads();
    #pragma unroll
    for (int s = 128; s > 0; s >>= 1) {
        if (threadIdx.x < s) sh[threadIdx.x] += sh[threadIdx.x + s];
        __syncthreads();
    }
    if (threadIdx.x == 0) {
        float perp = expf(-sh[0]);
        float loss = 1.25f * (sumsq[0] / 4194304.0f);
        if (isnan(loss) || isinf(loss)) loss = 0.1f;
        out[OFF_LOSS] = loss;
        out[OFF_PERP] = perp;
    }
}

extern "C" void kernel_launch(void* const* d_in, const int* in_sizes, int n_in,
                              void* d_out, int out_size, void* d_ws, size_t ws_size,
                              hipStream_t stream) {
    const float* x = (const float*)d_in[0];   // [32,128,32,32] fp32 NCHW
    const float* w = (const float*)d_in[1];   // [4096,128] fp32
    float* out = (float*)d_out;
    char* ws = (char*)d_ws;

    unsigned long long* packed = (unsigned long long*)(ws + WS_PACKED);
    float* counts = (float*)(ws + WS_COUNTS);
    float* sumsq  = (float*)(ws + WS_SUMSQ);
    float* wsq    = (float*)(ws + WS_WSQ);

    // init workspace (poisoned 0xAA before every launch)
    hipMemsetAsync(packed, 0xFF, (size_t)N_FLAT * 8, stream);        // u64 max
    hipMemsetAsync(counts, 0, (size_t)K_CODES * 4 + 32, stream);     // counts+sumsq

    wsq_kernel<<<K_CODES, 64, 0, stream>>>(w, wsq);

    dim3 g2(128, 8);
    dist_argmin<<<g2, 256, 0, stream>>>(x, w, wsq, packed, out + OFF_ENC);

    combine<<<N_FLAT / 256, 256, 0, stream>>>(packed, out + OFF_IDX,
                                              out + OFF_ENC, counts);

    quantize_loss<<<4194304 / 256, 256, 0, stream>>>(x, w, out + OFF_IDX,
                                                     out + OFF_Q, sumsq);

    finalize<<<1, 256, 0, stream>>>(counts, sumsq, out);
}

// Round 2
// 1681.233 us; speedup vs baseline: 1.5569x; 1.5569x over previous
//
#include <hip/hip_runtime.h>
#include <stdint.h>
#include <math.h>

#define K_CODES 4096
#define DIM 128
#define N_FLAT 32768      // 32 * 32 * 32
#define HW 1024           // 32*32 spatial per batch

// output offsets (in floats), concat order: quantized_st, loss, perplexity, encodings, indices
#define OFF_Q    0
#define OFF_LOSS 4194304
#define OFF_PERP 4194305
#define OFF_ENC  4194306
#define OFF_IDX  138412034

// workspace offsets (bytes)
#define WS_PACKED 0                       // 32768 * 8 = 262144
#define WS_COUNTS 262144                  // 4096 * 4 = 16384
#define WS_SUMSQ  278528                  // 4 bytes
#define WS_WSQ    278544                  // 4096 * 4

// ---------------- K1: w_sq[k] = sum_d w[k][d]^2 ----------------
__global__ __launch_bounds__(64) void wsq_kernel(const float* __restrict__ w,
                                                 float* __restrict__ wsq) {
    int k = blockIdx.x;
    int lane = threadIdx.x;
    float a = w[k * DIM + lane];
    float b = w[k * DIM + lane + 64];
    float s = a * a + b * b;
    #pragma unroll
    for (int o = 32; o > 0; o >>= 1) s += __shfl_down(s, o, 64);
    if (lane == 0) wsq[k] = s;
}

// ---------------- K2: distances + split-K argmin (+ zero-fill encodings) ----
// grid (512 n-tiles, 4 k-chunks), block 256.
// Block: 64-n tile in LDS; each wave handles 256 codes; lane = n_local.
// Code index is wave-uniform -> readfirstlane -> w/wsq via scalar loads.
__global__ __launch_bounds__(256, 4) void dist_argmin(
    const float* __restrict__ x, const float* __restrict__ w,
    const float* __restrict__ wsq, unsigned long long* __restrict__ packed,
    float* __restrict__ enc)
{
    __shared__ float xt[64 * DIM];                 // [dpair][n][2] interleave, 32 KB
    __shared__ float xsq_sm[64];
    __shared__ unsigned long long wbest[4][64];

    const int tid  = threadIdx.x;
    const int lane = tid & 63;
    const int wave = tid >> 6;
    const int n0   = blockIdx.x * 64;              // 64 | 1024 -> same batch b for tile
    const int b    = n0 >> 10;
    const int hw0  = n0 & 1023;
    const int kb0  = blockIdx.y * 1024;

    // ---- stage x tile: xt[(c>>1)*128 + nl*2 + (c&1)] = x[b][c][hw0+nl] ----
    {
        const float* xb = x + (size_t)b * (DIM * HW) + hw0;
        #pragma unroll 4
        for (int it = 0; it < 32; ++it) {
            int c  = it * 4 + (tid >> 6);
            int nl = tid & 63;
            float v = xb[c * HW + nl];             // coalesced across lanes
            xt[(c >> 1) * 128 + nl * 2 + (c & 1)] = v;
        }
    }
    __syncthreads();

    // ---- zero-fill this block's encodings rectangle (coalesced float2) ----
    // absolute float offset of enc rows is 8-byte aligned only -> float2
    {
        float2 z2; z2.x = 0.f; z2.y = 0.f;
        // 64 rows x 1024 floats = 512 float2 per row; 256 threads -> 2 iter/row
        for (int r = 0; r < 64; ++r) {
            float2* ep = (float2*)(enc + (size_t)(n0 + r) * K_CODES + kb0);
            ep[tid]       = z2;
            ep[tid + 256] = z2;
        }
    }

    // ---- x_sq per n (sequential d order, matches reference rounding path) ----
    if (tid < 64) {
        const float2* xt2 = (const float2*)xt;
        float s = 0.f;
        #pragma unroll
        for (int dp = 0; dp < 64; ++dp) {
            float2 v = xt2[dp * 64 + tid];
            s = fmaf(v.x, v.x, s);
            s = fmaf(v.y, v.y, s);
        }
        xsq_sm[tid] = s;
    }
    __syncthreads();

    const float2* xt2 = (const float2*)xt;
    const float xsq_r = xsq_sm[lane];

    float best = 3.4e38f;
    int bestk  = 0;

    const int kstart = kb0 + wave * 256;           // wave-uniform
    for (int kg = 0; kg < 256; kg += 4) {
        const int ks = __builtin_amdgcn_readfirstlane(kstart + kg);
        const float* wp = w + (size_t)ks * DIM;    // uniform -> s_load path
        float d0 = 0.f, d1 = 0.f, d2 = 0.f, d3 = 0.f;
        #pragma unroll 16
        for (int dp = 0; dp < 64; ++dp) {
            float2 xv = xt2[dp * 64 + lane];
            d0 = fmaf(xv.x, wp[          2 * dp    ], d0);
            d0 = fmaf(xv.y, wp[          2 * dp + 1], d0);
            d1 = fmaf(xv.x, wp[DIM     + 2 * dp    ], d1);
            d1 = fmaf(xv.y, wp[DIM     + 2 * dp + 1], d1);
            d2 = fmaf(xv.x, wp[2 * DIM + 2 * dp    ], d2);
            d2 = fmaf(xv.y, wp[2 * DIM + 2 * dp + 1], d2);
            d3 = fmaf(xv.x, wp[3 * DIM + 2 * dp    ], d3);
            d3 = fmaf(xv.y, wp[3 * DIM + 2 * dp + 1], d3);
        }
        // mirror reference association: ((x_sq - 2xy) + w_sq) + 1e-8
        float t0 = xsq_r - 2.0f * d0; t0 += wsq[ks];     t0 += 1e-8f;
        float t1 = xsq_r - 2.0f * d1; t1 += wsq[ks + 1]; t1 += 1e-8f;
        float t2 = xsq_r - 2.0f * d2; t2 += wsq[ks + 2]; t2 += 1e-8f;
        float t3 = xsq_r - 2.0f * d3; t3 += wsq[ks + 3]; t3 += 1e-8f;
        if (t0 < best) { best = t0; bestk = ks;     }
        if (t1 < best) { best = t1; bestk = ks + 1; }
        if (t2 < best) { best = t2; bestk = ks + 2; }
        if (t3 < best) { best = t3; bestk = ks + 3; }
    }

    // order-preserving float->uint map (dist can be slightly negative)
    unsigned u = __float_as_uint(best);
    u = (u & 0x80000000u) ? ~u : (u | 0x80000000u);
    wbest[wave][lane] = ((unsigned long long)u << 32) | (unsigned)bestk;
    __syncthreads();

    if (tid < 64) {
        unsigned long long m = wbest[0][tid];
        unsigned long long m1 = wbest[1][tid]; if (m1 < m) m = m1;
        unsigned long long m2 = wbest[2][tid]; if (m2 < m) m = m2;
        unsigned long long m3 = wbest[3][tid]; if (m3 < m) m = m3;
        atomicMin(&packed[n0 + tid], m);
    }
}

// ---------------- K3: combine -> indices, one-hot 1.0, counts ---------------
__global__ __launch_bounds__(256) void combine(
    const unsigned long long* __restrict__ packed,
    float* __restrict__ idxf, float* __restrict__ enc,
    float* __restrict__ counts)
{
    int n = blockIdx.x * 256 + threadIdx.x;
    unsigned k = (unsigned)(packed[n] & 0xFFFFFFFFu);
    idxf[n] = (float)k;
    enc[(size_t)n * K_CODES + k] = 1.0f;
    atomicAdd(&counts[k], 1.0f);
}

// ---------------- K4: gather codebook -> quantized_st (NCHW) + loss sum -----
__global__ __launch_bounds__(256) void quantize_loss(
    const float* __restrict__ x, const float* __restrict__ w,
    const float* __restrict__ idxf, float* __restrict__ outq,
    float* __restrict__ sumsq)
{
    int tid = blockIdx.x * 256 + threadIdx.x;   // NCHW element index
    int hw = tid & 1023;
    int c  = (tid >> 10) & 127;
    int b  = tid >> 17;
    int n  = (b << 10) | hw;
    int k  = (int)idxf[n];
    float q  = w[k * DIM + c];
    float xv = x[tid];
    float diff = q - xv;                 // fl(q - x), matches reference rounding
    outq[tid] = xv + diff;               // quantized_st = x + (q - x)
    float s = diff * diff;
    #pragma unroll
    for (int o = 32; o > 0; o >>= 1) s += __shfl_down(s, o, 64);
    __shared__ float ls[4];
    if ((threadIdx.x & 63) == 0) ls[threadIdx.x >> 6] = s;
    __syncthreads();
    if (threadIdx.x == 0) atomicAdd(sumsq, ls[0] + ls[1] + ls[2] + ls[3]);
}

// ---------------- K5: loss + perplexity ------------------------------------
__global__ __launch_bounds__(256) void finalize(
    const float* __restrict__ counts, const float* __restrict__ sumsq,
    float* __restrict__ out)
{
    __shared__ float sh[256];
    float h = 0.f;
    for (int k = threadIdx.x; k < K_CODES; k += 256) {
        float p = counts[k] * (1.0f / N_FLAT);
        h += p * logf(p + 1e-10f);
    }
    sh[threadIdx.x] = h;
    __syncthreads();
    #pragma unroll
    for (int s = 128; s > 0; s >>= 1) {
        if (threadIdx.x < s) sh[threadIdx.x] += sh[threadIdx.x + s];
        __syncthreads();
    }
    if (threadIdx.x == 0) {
        float perp = expf(-sh[0]);
        float loss = 1.25f * (sumsq[0] / 4194304.0f);
        if (isnan(loss) || isinf(loss)) loss = 0.1f;
        out[OFF_LOSS] = loss;
        out[OFF_PERP] = perp;
    }
}

extern "C" void kernel_launch(void* const* d_in, const int* in_sizes, int n_in,
                              void* d_out, int out_size, void* d_ws, size_t ws_size,
                              hipStream_t stream) {
    const float* x = (const float*)d_in[0];   // [32,128,32,32] fp32 NCHW
    const float* w = (const float*)d_in[1];   // [4096,128] fp32
    float* out = (float*)d_out;
    char* ws = (char*)d_ws;

    unsigned long long* packed = (unsigned long long*)(ws + WS_PACKED);
    float* counts = (float*)(ws + WS_COUNTS);
    float* sumsq  = (float*)(ws + WS_SUMSQ);
    float* wsq    = (float*)(ws + WS_WSQ);

    // init workspace (poisoned 0xAA before every launch)
    hipMemsetAsync(packed, 0xFF, (size_t)N_FLAT * 8, stream);        // u64 max
    hipMemsetAsync(counts, 0, (size_t)K_CODES * 4 + 32, stream);     // counts+sumsq

    wsq_kernel<<<K_CODES, 64, 0, stream>>>(w, wsq);

    dim3 g2(512, 4);
    dist_argmin<<<g2, 256, 0, stream>>>(x, w, wsq, packed, out + OFF_ENC);

    combine<<<N_FLAT / 256, 256, 0, stream>>>(packed, out + OFF_IDX,
                                              out + OFF_ENC, counts);

    quantize_loss<<<4194304 / 256, 256, 0, stream>>>(x, w, out + OFF_IDX,
                                                     out + OFF_Q, sumsq);

    finalize<<<1, 256, 0, stream>>>(counts, sumsq, out);
}

// Round 3
// 1479.483 us; speedup vs baseline: 1.7692x; 1.1364x over previous
//
#include <hip/hip_runtime.h>
#include <stdint.h>
#include <math.h>

#define K_CODES 4096
#define DIM 128
#define N_FLAT 32768      // 32 * 32 * 32
#define HW 1024           // 32*32 spatial per batch

// output offsets (in floats), concat order: quantized_st, loss, perplexity, encodings, indices
#define OFF_Q    0
#define OFF_LOSS 4194304
#define OFF_PERP 4194305
#define OFF_ENC  4194306
#define OFF_IDX  138412034

// workspace offsets (bytes)
#define WS_PACKED 0                       // 32768 * 8 = 262144
#define WS_COUNTS 262144                  // 4096 * 4 = 16384
#define WS_SUMSQ  278528                  // 4 bytes (+pad)
#define WS_WSQ    278544                  // 4096 * 4 = 16384
#define WS_XSQ    294928                  // 32768 * 4 = 131072

// ---------------- K1: w_sq[k] = sum_d w[k][d]^2 ----------------
__global__ __launch_bounds__(64) void wsq_kernel(const float* __restrict__ w,
                                                 float* __restrict__ wsq) {
    int k = blockIdx.x;
    int lane = threadIdx.x;
    float a = w[k * DIM + lane];
    float b = w[k * DIM + lane + 64];
    float s = a * a + b * b;
    #pragma unroll
    for (int o = 32; o > 0; o >>= 1) s += __shfl_down(s, o, 64);
    if (lane == 0) wsq[k] = s;
}

// ---------------- K1b: x_sq[n] = sum_c x[b][c][hw]^2 (strict c order) ------
__global__ __launch_bounds__(256) void xsq_kernel(const float* __restrict__ x,
                                                  float* __restrict__ xsq) {
    int n = blockIdx.x * 256 + threadIdx.x;
    int b = n >> 10, hw = n & 1023;
    const float* xb = x + (size_t)b * (DIM * HW) + hw;
    float s = 0.f;
    #pragma unroll
    for (int c = 0; c < DIM; ++c) {
        float v = xb[c * HW];
        s = fmaf(v, v, s);
    }
    xsq[n] = s;
}

// ---------------- K2: register-tiled distance GEMM + split-K argmin --------
// grid (256 n-tiles, 32 k-tiles), block 256 = 16 kthr x 16 nthr, thread 8n x 8k.
// Block tile 128n x 128k, d chunked by 32 through LDS. Also zero-fills its
// 128x128 encodings rectangle (coalesced float2, issued first to drain early).
__global__ __launch_bounds__(256, 4) void dist_argmin(
    const float* __restrict__ x, const float* __restrict__ w,
    const float* __restrict__ wsq, const float* __restrict__ xsq,
    unsigned long long* __restrict__ packed, float* __restrict__ enc)
{
    __shared__ float sm[32 * 128 + 32 * 132 + 256];   // xs | wsd | xsq_s,wsq_s
    float* xs    = sm;                 // [32][128]
    float* wsd   = sm + 4096;          // [32][132] (padded, 16B-aligned rows)
    float* xsq_s = sm + 4096 + 4224;   // [128]
    float* wsq_s = xsq_s + 128;        // [128]

    const int tid  = threadIdx.x;
    const int kthr = tid & 15;
    const int nthr = tid >> 4;
    const int n0   = blockIdx.x * 128;           // same batch b for whole tile
    const int k0   = blockIdx.y * 128;
    const int b    = n0 >> 10;
    const int hw0  = n0 & 1023;

    const float* xg = x + (size_t)b * (DIM * HW) + hw0;  // xg[d*HW + n]
    const float* wg = w + (size_t)k0 * DIM;              // wg[k*DIM + d]

    // ---- zero-fill encodings rectangle first (writes drain under compute) --
    {
        float2 z2; z2.x = 0.f; z2.y = 0.f;
        float* ebase = enc + (size_t)n0 * K_CODES + k0;  // 8B-aligned only
        #pragma unroll 4
        for (int i = 0; i < 32; ++i) {
            int idx = i * 256 + tid;
            int r = idx >> 6, c2 = idx & 63;
            *(float2*)(ebase + (size_t)r * K_CODES + c2 * 2) = z2;
        }
    }

    // ---- stage per-row norms ----
    if (tid < 128) {
        xsq_s[tid] = xsq[n0 + tid];
        wsq_s[tid] = wsq[k0 + tid];
    }

    float acc[8][8];
    #pragma unroll
    for (int i = 0; i < 8; ++i)
        #pragma unroll
        for (int j = 0; j < 8; ++j) acc[i][j] = 0.f;

    for (int d0 = 0; d0 < DIM; d0 += 32) {
        __syncthreads();
        // stage x chunk: xs[dc][n], coalesced float4
        #pragma unroll
        for (int i = 0; i < 4; ++i) {
            int idx4 = i * 256 + tid;
            int dc = idx4 >> 5, nc = (idx4 & 31) << 2;
            float4 v = *(const float4*)(xg + (d0 + dc) * HW + nc);
            *(float4*)(xs + dc * 128 + nc) = v;
        }
        // stage w chunk transposed: wsd[dc][k], float4 read + scalar scatter
        #pragma unroll
        for (int i = 0; i < 4; ++i) {
            int idx4 = i * 256 + tid;
            int k = idx4 >> 3, dq = (idx4 & 7) << 2;
            float4 v = *(const float4*)(wg + k * DIM + d0 + dq);
            wsd[(dq + 0) * 132 + k] = v.x;
            wsd[(dq + 1) * 132 + k] = v.y;
            wsd[(dq + 2) * 132 + k] = v.z;
            wsd[(dq + 3) * 132 + k] = v.w;
        }
        __syncthreads();

        #pragma unroll 2
        for (int dc = 0; dc < 32; ++dc) {
            float4 xa  = *(float4*)(xs + dc * 128 + nthr * 8);
            float4 xb4 = *(float4*)(xs + dc * 128 + nthr * 8 + 4);
            float4 wa  = *(float4*)(wsd + dc * 132 + kthr * 8);
            float4 wb  = *(float4*)(wsd + dc * 132 + kthr * 8 + 4);
            float xr[8] = {xa.x, xa.y, xa.z, xa.w, xb4.x, xb4.y, xb4.z, xb4.w};
            float wr[8] = {wa.x, wa.y, wa.z, wa.w, wb.x, wb.y, wb.z, wb.w};
            #pragma unroll
            for (int ni = 0; ni < 8; ++ni)
                #pragma unroll
                for (int ki = 0; ki < 8; ++ki)
                    acc[ni][ki] = fmaf(xr[ni], wr[ki], acc[ni][ki]);
        }
    }

    // ---- epilogue: distances, per-thread argmin over its 8 k's ------------
    float xsq_r[8], wsq_r[8];
    #pragma unroll
    for (int i = 0; i < 8; ++i) {
        xsq_r[i] = xsq_s[nthr * 8 + i];
        wsq_r[i] = wsq_s[kthr * 8 + i];
    }

    unsigned long long bp[8];
    #pragma unroll
    for (int ni = 0; ni < 8; ++ni) {
        float best = 3.4e38f;
        int bestk = 0;
        #pragma unroll
        for (int ki = 0; ki < 8; ++ki) {
            // mirror reference association: ((x_sq - 2xy) + w_sq) + 1e-8
            float t = xsq_r[ni] - 2.0f * acc[ni][ki];
            t += wsq_r[ki];
            t += 1e-8f;
            if (t < best) { best = t; bestk = k0 + kthr * 8 + ki; }
        }
        unsigned u = __float_as_uint(best);
        u = (u & 0x80000000u) ? ~u : (u | 0x80000000u);
        bp[ni] = ((unsigned long long)u << 32) | (unsigned)bestk;
    }

    // ---- block reduce over 16 kthr via LDS (reuse staging buffer) ---------
    __syncthreads();
    unsigned long long* ub = (unsigned long long*)sm;   // [16 kthr][128 n]
    #pragma unroll
    for (int ni = 0; ni < 8; ++ni)
        ub[kthr * 128 + nthr * 8 + ni] = bp[ni];
    __syncthreads();

    if (tid < 128) {
        unsigned long long m = ub[tid];
        #pragma unroll
        for (int j = 1; j < 16; ++j) {
            unsigned long long v = ub[j * 128 + tid];
            if (v < m) m = v;
        }
        atomicMin(&packed[n0 + tid], m);
    }
}

// ---------------- K3: combine -> indices, one-hot 1.0, counts ---------------
__global__ __launch_bounds__(256) void combine(
    const unsigned long long* __restrict__ packed,
    float* __restrict__ idxf, float* __restrict__ enc,
    float* __restrict__ counts)
{
    int n = blockIdx.x * 256 + threadIdx.x;
    unsigned k = (unsigned)(packed[n] & 0xFFFFFFFFu);
    idxf[n] = (float)k;
    enc[(size_t)n * K_CODES + k] = 1.0f;
    atomicAdd(&counts[k], 1.0f);
}

// ---------------- K4: gather codebook -> quantized_st (NCHW) + loss sum -----
__global__ __launch_bounds__(256) void quantize_loss(
    const float* __restrict__ x, const float* __restrict__ w,
    const float* __restrict__ idxf, float* __restrict__ outq,
    float* __restrict__ sumsq)
{
    int tid = blockIdx.x * 256 + threadIdx.x;   // NCHW element index
    int hw = tid & 1023;
    int c  = (tid >> 10) & 127;
    int b  = tid >> 17;
    int n  = (b << 10) | hw;
    int k  = (int)idxf[n];
    float q  = w[k * DIM + c];
    float xv = x[tid];
    float diff = q - xv;                 // fl(q - x), matches reference rounding
    outq[tid] = xv + diff;               // quantized_st = x + (q - x)
    float s = diff * diff;
    #pragma unroll
    for (int o = 32; o > 0; o >>= 1) s += __shfl_down(s, o, 64);
    __shared__ float ls[4];
    if ((threadIdx.x & 63) == 0) ls[threadIdx.x >> 6] = s;
    __syncthreads();
    if (threadIdx.x == 0) atomicAdd(sumsq, ls[0] + ls[1] + ls[2] + ls[3]);
}

// ---------------- K5: loss + perplexity ------------------------------------
__global__ __launch_bounds__(256) void finalize(
    const float* __restrict__ counts, const float* __restrict__ sumsq,
    float* __restrict__ out)
{
    __shared__ float sh[256];
    float h = 0.f;
    for (int k = threadIdx.x; k < K_CODES; k += 256) {
        float p = counts[k] * (1.0f / N_FLAT);
        h += p * logf(p + 1e-10f);
    }
    sh[threadIdx.x] = h;
    __syncthreads();
    #pragma unroll
    for (int s = 128; s > 0; s >>= 1) {
        if (threadIdx.x < s) sh[threadIdx.x] += sh[threadIdx.x + s];
        __syncthreads();
    }
    if (threadIdx.x == 0) {
        float perp = expf(-sh[0]);
        float loss = 1.25f * (sumsq[0] / 4194304.0f);
        if (isnan(loss) || isinf(loss)) loss = 0.1f;
        out[OFF_LOSS] = loss;
        out[OFF_PERP] = perp;
    }
}

extern "C" void kernel_launch(void* const* d_in, const int* in_sizes, int n_in,
                              void* d_out, int out_size, void* d_ws, size_t ws_size,
                              hipStream_t stream) {
    const float* x = (const float*)d_in[0];   // [32,128,32,32] fp32 NCHW
    const float* w = (const float*)d_in[1];   // [4096,128] fp32
    float* out = (float*)d_out;
    char* ws = (char*)d_ws;

    unsigned long long* packed = (unsigned long long*)(ws + WS_PACKED);
    float* counts = (float*)(ws + WS_COUNTS);
    float* sumsq  = (float*)(ws + WS_SUMSQ);
    float* wsq    = (float*)(ws + WS_WSQ);
    float* xsq    = (float*)(ws + WS_XSQ);

    // init workspace (poisoned 0xAA before every launch)
    hipMemsetAsync(packed, 0xFF, (size_t)N_FLAT * 8, stream);        // u64 max
    hipMemsetAsync(counts, 0, (size_t)K_CODES * 4 + 32, stream);     // counts+sumsq

    wsq_kernel<<<K_CODES, 64, 0, stream>>>(w, wsq);
    xsq_kernel<<<N_FLAT / 256, 256, 0, stream>>>(x, xsq);

    dim3 g2(256, 32);
    dist_argmin<<<g2, 256, 0, stream>>>(x, w, wsq, xsq, packed, out + OFF_ENC);

    combine<<<N_FLAT / 256, 256, 0, stream>>>(packed, out + OFF_IDX,
                                              out + OFF_ENC, counts);

    quantize_loss<<<4194304 / 256, 256, 0, stream>>>(x, w, out + OFF_IDX,
                                                     out + OFF_Q, sumsq);

    finalize<<<1, 256, 0, stream>>>(counts, sumsq, out);
}

// Round 4
// 1310.268 us; speedup vs baseline: 1.9977x; 1.1291x over previous
//
#include <hip/hip_runtime.h>
#include <stdint.h>
#include <math.h>

#define K_CODES 4096
#define DIM 128
#define N_FLAT 32768      // 32 * 32 * 32
#define HW 1024           // 32*32 spatial per batch

// output offsets (in floats), concat order: quantized_st, loss, perplexity, encodings, indices
#define OFF_Q    0
#define OFF_LOSS 4194304
#define OFF_PERP 4194305
#define OFF_ENC  4194306
#define OFF_IDX  138412034

// workspace offsets (bytes)
#define WS_PACKED 0                       // 32768 * 8 = 262144
#define WS_COUNTS 262144                  // 4096 * 4 = 16384
#define WS_SUMSQ  278528                  // 4 bytes (+pad)
#define WS_WSQ    278544                  // 4096 * 4 = 16384
#define WS_XSQ    294928                  // 32768 * 4 = 131072

// wsd layout: 8-float k-group padded to 10 floats (40B group stride -> 16
// distinct banks for kthr=0..15), row stride 162 floats (even: keeps 8B
// alignment; not 0 mod 32: staging writes spread to 2-way = free)
#define WROW 162

// ---------------- K1: w_sq[k] = sum_d w[k][d]^2 ----------------
__global__ __launch_bounds__(64) void wsq_kernel(const float* __restrict__ w,
                                                 float* __restrict__ wsq) {
    int k = blockIdx.x;
    int lane = threadIdx.x;
    float a = w[k * DIM + lane];
    float b = w[k * DIM + lane + 64];
    float s = a * a + b * b;
    #pragma unroll
    for (int o = 32; o > 0; o >>= 1) s += __shfl_down(s, o, 64);
    if (lane == 0) wsq[k] = s;
}

// ---------------- K1b: x_sq[n] = sum_c x[b][c][hw]^2 (strict c order) ------
__global__ __launch_bounds__(256) void xsq_kernel(const float* __restrict__ x,
                                                  float* __restrict__ xsq) {
    int n = blockIdx.x * 256 + threadIdx.x;
    int b = n >> 10, hw = n & 1023;
    const float* xb = x + (size_t)b * (DIM * HW) + hw;
    float s = 0.f;
    #pragma unroll
    for (int c = 0; c < DIM; ++c) {
        float v = xb[c * HW];
        s = fmaf(v, v, s);
    }
    xsq[n] = s;
}

// ---------------- K2: register-tiled distance GEMM + split-K argmin --------
// grid (256 n-tiles, 32 k-tiles), block 256 = 16 kthr x 16 nthr, thread 8n x 8k.
// Block tile 128n x 128k, d chunked by 32 through LDS. Also zero-fills its
// 128x128 encodings rectangle (coalesced float2, issued first to drain early).
__global__ __launch_bounds__(256, 4) void dist_argmin(
    const float* __restrict__ x, const float* __restrict__ w,
    const float* __restrict__ wsq, const float* __restrict__ xsq,
    unsigned long long* __restrict__ packed, float* __restrict__ enc)
{
    __shared__ float sm[32 * 128 + 32 * WROW + 256];  // xs | wsd | xsq_s,wsq_s
    float* xs    = sm;                    // [32][128]
    float* wsd   = sm + 4096;             // [32][WROW], k-group g at col g*10
    float* xsq_s = sm + 4096 + 32 * WROW; // [128]
    float* wsq_s = xsq_s + 128;           // [128]

    const int tid  = threadIdx.x;
    const int kthr = tid & 15;
    const int nthr = tid >> 4;
    const int n0   = blockIdx.x * 128;           // same batch b for whole tile
    const int k0   = blockIdx.y * 128;
    const int b    = n0 >> 10;
    const int hw0  = n0 & 1023;

    const float* xg = x + (size_t)b * (DIM * HW) + hw0;  // xg[d*HW + n]
    const float* wg = w + (size_t)k0 * DIM;              // wg[k*DIM + d]

    // ---- zero-fill encodings rectangle first (writes drain under compute) --
    {
        float2 z2; z2.x = 0.f; z2.y = 0.f;
        float* ebase = enc + (size_t)n0 * K_CODES + k0;  // 8B-aligned only
        #pragma unroll 4
        for (int i = 0; i < 32; ++i) {
            int idx = i * 256 + tid;
            int r = idx >> 6, c2 = idx & 63;
            *(float2*)(ebase + (size_t)r * K_CODES + c2 * 2) = z2;
        }
    }

    // ---- stage per-row norms ----
    if (tid < 128) {
        xsq_s[tid] = xsq[n0 + tid];
        wsq_s[tid] = wsq[k0 + tid];
    }

    float acc[8][8];
    #pragma unroll
    for (int i = 0; i < 8; ++i)
        #pragma unroll
        for (int j = 0; j < 8; ++j) acc[i][j] = 0.f;

    for (int d0 = 0; d0 < DIM; d0 += 32) {
        __syncthreads();
        // stage x chunk: xs[dc][n], coalesced float4
        #pragma unroll
        for (int i = 0; i < 4; ++i) {
            int idx4 = i * 256 + tid;
            int dc = idx4 >> 5, nc = (idx4 & 31) << 2;
            float4 v = *(const float4*)(xg + (d0 + dc) * HW + nc);
            *(float4*)(xs + dc * 128 + nc) = v;
        }
        // stage w chunk transposed: wsd[dc][g*10 + k&7], float4 read + scatter
        #pragma unroll
        for (int i = 0; i < 4; ++i) {
            int idx4 = i * 256 + tid;
            int k = idx4 >> 3, dq = (idx4 & 7) << 2;
            int col = (k >> 3) * 10 + (k & 7);
            float4 v = *(const float4*)(wg + k * DIM + d0 + dq);
            wsd[(dq + 0) * WROW + col] = v.x;
            wsd[(dq + 1) * WROW + col] = v.y;
            wsd[(dq + 2) * WROW + col] = v.z;
            wsd[(dq + 3) * WROW + col] = v.w;
        }
        __syncthreads();

        #pragma unroll 2
        for (int dc = 0; dc < 32; ++dc) {
            float4 xa  = *(float4*)(xs + dc * 128 + nthr * 8);
            float4 xb4 = *(float4*)(xs + dc * 128 + nthr * 8 + 4);
            const float* wp = wsd + dc * WROW + kthr * 10;
            float2 w01 = *(float2*)(wp + 0);
            float2 w23 = *(float2*)(wp + 2);
            float2 w45 = *(float2*)(wp + 4);
            float2 w67 = *(float2*)(wp + 6);
            float xr[8] = {xa.x, xa.y, xa.z, xa.w, xb4.x, xb4.y, xb4.z, xb4.w};
            float wr[8] = {w01.x, w01.y, w23.x, w23.y,
                           w45.x, w45.y, w67.x, w67.y};
            #pragma unroll
            for (int ni = 0; ni < 8; ++ni)
                #pragma unroll
                for (int ki = 0; ki < 8; ++ki)
                    acc[ni][ki] = fmaf(xr[ni], wr[ki], acc[ni][ki]);
        }
    }

    // ---- epilogue: distances, per-thread argmin over its 8 k's ------------
    float xsq_r[8], wsq_r[8];
    #pragma unroll
    for (int i = 0; i < 8; ++i) {
        xsq_r[i] = xsq_s[nthr * 8 + i];
        wsq_r[i] = wsq_s[kthr * 8 + i];
    }

    unsigned long long bp[8];
    #pragma unroll
    for (int ni = 0; ni < 8; ++ni) {
        float best = 3.4e38f;
        int bestk = 0;
        #pragma unroll
        for (int ki = 0; ki < 8; ++ki) {
            // mirror reference association: ((x_sq - 2xy) + w_sq) + 1e-8
            float t = xsq_r[ni] - 2.0f * acc[ni][ki];
            t += wsq_r[ki];
            t += 1e-8f;
            if (t < best) { best = t; bestk = k0 + kthr * 8 + ki; }
        }
        unsigned u = __float_as_uint(best);
        u = (u & 0x80000000u) ? ~u : (u | 0x80000000u);
        bp[ni] = ((unsigned long long)u << 32) | (unsigned)bestk;
    }

    // ---- block reduce over 16 kthr via LDS (reuse staging buffer) ---------
    __syncthreads();
    unsigned long long* ub = (unsigned long long*)sm;   // [16 kthr][128 n]
    #pragma unroll
    for (int ni = 0; ni < 8; ++ni)
        ub[kthr * 128 + nthr * 8 + ni] = bp[ni];
    __syncthreads();

    if (tid < 128) {
        unsigned long long m = ub[tid];
        #pragma unroll
        for (int j = 1; j < 16; ++j) {
            unsigned long long v = ub[j * 128 + tid];
            if (v < m) m = v;
        }
        atomicMin(&packed[n0 + tid], m);
    }
}

// ---------------- K3: combine -> indices, one-hot 1.0, counts ---------------
__global__ __launch_bounds__(256) void combine(
    const unsigned long long* __restrict__ packed,
    float* __restrict__ idxf, float* __restrict__ enc,
    float* __restrict__ counts)
{
    int n = blockIdx.x * 256 + threadIdx.x;
    unsigned k = (unsigned)(packed[n] & 0xFFFFFFFFu);
    idxf[n] = (float)k;
    enc[(size_t)n * K_CODES + k] = 1.0f;
    atomicAdd(&counts[k], 1.0f);
}

// ---------------- K4: gather codebook -> quantized_st (NCHW) + loss sum -----
__global__ __launch_bounds__(256) void quantize_loss(
    const float* __restrict__ x, const float* __restrict__ w,
    const float* __restrict__ idxf, float* __restrict__ outq,
    float* __restrict__ sumsq)
{
    int tid = blockIdx.x * 256 + threadIdx.x;   // NCHW element index
    int hw = tid & 1023;
    int c  = (tid >> 10) & 127;
    int b  = tid >> 17;
    int n  = (b << 10) | hw;
    int k  = (int)idxf[n];
    float q  = w[k * DIM + c];
    float xv = x[tid];
    float diff = q - xv;                 // fl(q - x), matches reference rounding
    outq[tid] = xv + diff;               // quantized_st = x + (q - x)
    float s = diff * diff;
    #pragma unroll
    for (int o = 32; o > 0; o >>= 1) s += __shfl_down(s, o, 64);
    __shared__ float ls[4];
    if ((threadIdx.x & 63) == 0) ls[threadIdx.x >> 6] = s;
    __syncthreads();
    if (threadIdx.x == 0) atomicAdd(sumsq, ls[0] + ls[1] + ls[2] + ls[3]);
}

// ---------------- K5: loss + perplexity ------------------------------------
__global__ __launch_bounds__(256) void finalize(
    const float* __restrict__ counts, const float* __restrict__ sumsq,
    float* __restrict__ out)
{
    __shared__ float sh[256];
    float h = 0.f;
    for (int k = threadIdx.x; k < K_CODES; k += 256) {
        float p = counts[k] * (1.0f / N_FLAT);
        h += p * logf(p + 1e-10f);
    }
    sh[threadIdx.x] = h;
    __syncthreads();
    #pragma unroll
    for (int s = 128; s > 0; s >>= 1) {
        if (threadIdx.x < s) sh[threadIdx.x] += sh[threadIdx.x + s];
        __syncthreads();
    }
    if (threadIdx.x == 0) {
        float perp = expf(-sh[0]);
        float loss = 1.25f * (sumsq[0] / 4194304.0f);
        if (isnan(loss) || isinf(loss)) loss = 0.1f;
        out[OFF_LOSS] = loss;
        out[OFF_PERP] = perp;
    }
}

extern "C" void kernel_launch(void* const* d_in, const int* in_sizes, int n_in,
                              void* d_out, int out_size, void* d_ws, size_t ws_size,
                              hipStream_t stream) {
    const float* x = (const float*)d_in[0];   // [32,128,32,32] fp32 NCHW
    const float* w = (const float*)d_in[1];   // [4096,128] fp32
    float* out = (float*)d_out;
    char* ws = (char*)d_ws;

    unsigned long long* packed = (unsigned long long*)(ws + WS_PACKED);
    float* counts = (float*)(ws + WS_COUNTS);
    float* sumsq  = (float*)(ws + WS_SUMSQ);
    float* wsq    = (float*)(ws + WS_WSQ);
    float* xsq    = (float*)(ws + WS_XSQ);

    // init workspace (poisoned 0xAA before every launch)
    hipMemsetAsync(packed, 0xFF, (size_t)N_FLAT * 8, stream);        // u64 max
    hipMemsetAsync(counts, 0, (size_t)K_CODES * 4 + 32, stream);     // counts+sumsq

    wsq_kernel<<<K_CODES, 64, 0, stream>>>(w, wsq);
    xsq_kernel<<<N_FLAT / 256, 256, 0, stream>>>(x, xsq);

    dim3 g2(256, 32);
    dist_argmin<<<g2, 256, 0, stream>>>(x, w, wsq, xsq, packed, out + OFF_ENC);

    combine<<<N_FLAT / 256, 256, 0, stream>>>(packed, out + OFF_IDX,
                                              out + OFF_ENC, counts);

    quantize_loss<<<4194304 / 256, 256, 0, stream>>>(x, w, out + OFF_IDX,
                                                     out + OFF_Q, sumsq);

    finalize<<<1, 256, 0, stream>>>(counts, sumsq, out);
}

// Round 5
// 1104.220 us; speedup vs baseline: 2.3705x; 1.1866x over previous
//
#include <hip/hip_runtime.h>
#include <stdint.h>
#include <math.h>

#define K_CODES 4096
#define DIM 128
#define N_FLAT 32768      // 32 * 32 * 32
#define HW 1024           // 32*32 spatial per batch

// output offsets (in floats), concat order: quantized_st, loss, perplexity, encodings, indices
#define OFF_Q    0
#define OFF_LOSS 4194304
#define OFF_PERP 4194305
#define OFF_ENC  4194306
#define OFF_IDX  138412034

// workspace offsets (bytes)
#define WS_PACKED 0                       // 32768 * 8 = 262144
#define WS_COUNTS 262144                  // 4096 * 4 = 16384
#define WS_WSQ    278528                  // 4096 * 4 = 16384
#define WS_XSQ    294912                  // 32768 * 4 = 131072
#define WS_PART   425984                  // 1024 * 4 = 4096

// wsd layout: 8-float k-group padded to 10 floats (40B group stride -> 16
// distinct banks for kthr=0..15), row stride 162 floats (even: keeps 8B
// alignment; not 0 mod 32: staging writes spread to 2-way = free)
#define WROW 162

// ---------------- K1: w_sq[k] = sum_d w[k][d]^2 ----------------
__global__ __launch_bounds__(64) void wsq_kernel(const float* __restrict__ w,
                                                 float* __restrict__ wsq) {
    int k = blockIdx.x;
    int lane = threadIdx.x;
    float a = w[k * DIM + lane];
    float b = w[k * DIM + lane + 64];
    float s = a * a + b * b;
    #pragma unroll
    for (int o = 32; o > 0; o >>= 1) s += __shfl_down(s, o, 64);
    if (lane == 0) wsq[k] = s;
}

// ---------------- K1b: x_sq[n] = sum_c x[b][c][hw]^2 (strict c order) ------
__global__ __launch_bounds__(256) void xsq_kernel(const float* __restrict__ x,
                                                  float* __restrict__ xsq) {
    int n = blockIdx.x * 256 + threadIdx.x;
    int b = n >> 10, hw = n & 1023;
    const float* xb = x + (size_t)b * (DIM * HW) + hw;
    float s = 0.f;
    #pragma unroll
    for (int c = 0; c < DIM; ++c) {
        float v = xb[c * HW];
        s = fmaf(v, v, s);
    }
    xsq[n] = s;
}

// ---------------- K2: register-tiled distance GEMM + split-K argmin --------
// grid (256 n-tiles, 32 k-tiles), block 256 = 16 kthr x 16 nthr, thread 8n x 8k.
// Block tile 128n x 128k, d chunked by 32 through LDS, register-prefetch of
// the next chunk's global data overlapping the current chunk's FMAs. Also
// zero-fills its 128x128 encodings rectangle (coalesced float2).
__global__ __launch_bounds__(256, 4) void dist_argmin(
    const float* __restrict__ x, const float* __restrict__ w,
    const float* __restrict__ wsq, const float* __restrict__ xsq,
    unsigned long long* __restrict__ packed, float* __restrict__ enc)
{
    __shared__ float sm[32 * 128 + 32 * WROW + 256];  // xs | wsd | xsq_s,wsq_s
    float* xs    = sm;                    // [32][128]
    float* wsd   = sm + 4096;             // [32][WROW], k-group g at col g*10
    float* xsq_s = sm + 4096 + 32 * WROW; // [128]
    float* wsq_s = xsq_s + 128;           // [128]

    const int tid  = threadIdx.x;
    const int kthr = tid & 15;
    const int nthr = tid >> 4;
    const int n0   = blockIdx.x * 128;           // same batch b for whole tile
    const int k0   = blockIdx.y * 128;
    const int b    = n0 >> 10;
    const int hw0  = n0 & 1023;

    const float* xg = x + (size_t)b * (DIM * HW) + hw0;  // xg[d*HW + n]
    const float* wg = w + (size_t)k0 * DIM;              // wg[k*DIM + d]

    // per-thread staging coordinates (fixed across chunks)
    const int sdc = tid >> 5;                 // x: d-row within chunk (i*8+sdc)
    const int snc = (tid & 31) << 2;          // x: n column (float4)
    const int sk  = tid >> 3;                 // w: k row (i*32+sk)
    const int sdq = (tid & 7) << 2;           // w: d quad within chunk

    // ---- prefetch chunk 0 into registers (loads issued before any stores) --
    float4 px[4], pw[4];
    #pragma unroll
    for (int i = 0; i < 4; ++i) {
        px[i] = *(const float4*)(xg + (i * 8 + sdc) * HW + snc);
        pw[i] = *(const float4*)(wg + (i * 32 + sk) * DIM + sdq);
    }

    // ---- stage per-row norms ----
    if (tid < 128) {
        xsq_s[tid] = xsq[n0 + tid];
        wsq_s[tid] = wsq[k0 + tid];
    }

    // ---- zero-fill encodings rectangle (writes drain under compute) -------
    {
        float2 z2; z2.x = 0.f; z2.y = 0.f;
        float* ebase = enc + (size_t)n0 * K_CODES + k0;  // 8B-aligned only
        #pragma unroll 4
        for (int i = 0; i < 32; ++i) {
            int idx = i * 256 + tid;
            int r = idx >> 6, c2 = idx & 63;
            *(float2*)(ebase + (size_t)r * K_CODES + c2 * 2) = z2;
        }
    }

    float acc[8][8];
    #pragma unroll
    for (int i = 0; i < 8; ++i)
        #pragma unroll
        for (int j = 0; j < 8; ++j) acc[i][j] = 0.f;

    #pragma unroll
    for (int c0 = 0; c0 < 4; ++c0) {
        const int d0 = c0 * 32;
        if (c0 > 0) __syncthreads();          // prev chunk's LDS reads done
        // write staged registers to LDS
        #pragma unroll
        for (int i = 0; i < 4; ++i) {
            *(float4*)(xs + (i * 8 + sdc) * 128 + snc) = px[i];
            int k = i * 32 + sk;
            int col = (k >> 3) * 10 + (k & 7);
            float4 v = pw[i];
            wsd[(sdq + 0) * WROW + col] = v.x;
            wsd[(sdq + 1) * WROW + col] = v.y;
            wsd[(sdq + 2) * WROW + col] = v.z;
            wsd[(sdq + 3) * WROW + col] = v.w;
        }
        // prefetch next chunk (overlaps with this chunk's FMAs)
        if (c0 < 3) {
            #pragma unroll
            for (int i = 0; i < 4; ++i) {
                px[i] = *(const float4*)(xg + (d0 + 32 + i * 8 + sdc) * HW + snc);
                pw[i] = *(const float4*)(wg + (i * 32 + sk) * DIM + d0 + 32 + sdq);
            }
        }
        __syncthreads();

        #pragma unroll 2
        for (int dc = 0; dc < 32; ++dc) {
            float4 xa  = *(float4*)(xs + dc * 128 + nthr * 8);
            float4 xb4 = *(float4*)(xs + dc * 128 + nthr * 8 + 4);
            const float* wp = wsd + dc * WROW + kthr * 10;
            float2 w01 = *(float2*)(wp + 0);
            float2 w23 = *(float2*)(wp + 2);
            float2 w45 = *(float2*)(wp + 4);
            float2 w67 = *(float2*)(wp + 6);
            float xr[8] = {xa.x, xa.y, xa.z, xa.w, xb4.x, xb4.y, xb4.z, xb4.w};
            float wr[8] = {w01.x, w01.y, w23.x, w23.y,
                           w45.x, w45.y, w67.x, w67.y};
            #pragma unroll
            for (int ni = 0; ni < 8; ++ni)
                #pragma unroll
                for (int ki = 0; ki < 8; ++ki)
                    acc[ni][ki] = fmaf(xr[ni], wr[ki], acc[ni][ki]);
        }
    }

    // ---- epilogue: distances, per-thread argmin over its 8 k's ------------
    float xsq_r[8], wsq_r[8];
    #pragma unroll
    for (int i = 0; i < 8; ++i) {
        xsq_r[i] = xsq_s[nthr * 8 + i];
        wsq_r[i] = wsq_s[kthr * 8 + i];
    }

    unsigned long long bp[8];
    #pragma unroll
    for (int ni = 0; ni < 8; ++ni) {
        float best = 3.4e38f;
        int bestk = 0;
        #pragma unroll
        for (int ki = 0; ki < 8; ++ki) {
            // mirror reference association: ((x_sq - 2xy) + w_sq) + 1e-8
            float t = xsq_r[ni] - 2.0f * acc[ni][ki];
            t += wsq_r[ki];
            t += 1e-8f;
            if (t < best) { best = t; bestk = k0 + kthr * 8 + ki; }
        }
        unsigned u = __float_as_uint(best);
        u = (u & 0x80000000u) ? ~u : (u | 0x80000000u);
        bp[ni] = ((unsigned long long)u << 32) | (unsigned)bestk;
    }

    // ---- block reduce over 16 kthr via LDS (reuse staging buffer) ---------
    __syncthreads();
    unsigned long long* ub = (unsigned long long*)sm;   // [16 kthr][128 n]
    #pragma unroll
    for (int ni = 0; ni < 8; ++ni)
        ub[kthr * 128 + nthr * 8 + ni] = bp[ni];
    __syncthreads();

    if (tid < 128) {
        unsigned long long m = ub[tid];
        #pragma unroll
        for (int j = 1; j < 16; ++j) {
            unsigned long long v = ub[j * 128 + tid];
            if (v < m) m = v;
        }
        atomicMin(&packed[n0 + tid], m);
    }
}

// ---------------- K3: combine -> indices, one-hot 1.0, counts ---------------
__global__ __launch_bounds__(256) void combine(
    const unsigned long long* __restrict__ packed,
    float* __restrict__ idxf, float* __restrict__ enc,
    float* __restrict__ counts)
{
    int n = blockIdx.x * 256 + threadIdx.x;
    unsigned k = (unsigned)(packed[n] & 0xFFFFFFFFu);
    idxf[n] = (float)k;
    enc[(size_t)n * K_CODES + k] = 1.0f;
    atomicAdd(&counts[k], 1.0f);
}

// ---------------- K4: gather -> quantized_st (NCHW) + per-block loss partial
// 1024 blocks x 256 threads x 4 iters x float4. NO global atomics: partial
// sum per block -> part[blockIdx] (the old one-atomic-per-block to a single
// address serialized ~16k device-scope RMWs ~ hundreds of us).
__global__ __launch_bounds__(256) void quantize_loss(
    const float* __restrict__ x, const float* __restrict__ w,
    const float* __restrict__ idxf, float* __restrict__ outq,
    float* __restrict__ part)
{
    const int base4 = (blockIdx.x * 256 + threadIdx.x) * 4;
    float s = 0.f;
    #pragma unroll
    for (int i = 0; i < 4; ++i) {
        int e  = base4 + i * 1048576;      // NCHW element index (x4 aligned)
        int hw = e & 1023;
        int c  = (e >> 10) & 127;
        int b  = e >> 17;
        int n  = (b << 10) | hw;           // multiple of 4
        float4 xv = *(const float4*)(x + e);
        float4 kf = *(const float4*)(idxf + n);
        float q0 = w[(int)kf.x * DIM + c];
        float q1 = w[(int)kf.y * DIM + c];
        float q2 = w[(int)kf.z * DIM + c];
        float q3 = w[(int)kf.w * DIM + c];
        float4 df; df.x = q0 - xv.x; df.y = q1 - xv.y;
                   df.z = q2 - xv.z; df.w = q3 - xv.w;
        float4 o;  o.x = xv.x + df.x; o.y = xv.y + df.y;
                   o.z = xv.z + df.z; o.w = xv.w + df.w;
        *(float4*)(outq + e) = o;
        s = fmaf(df.x, df.x, s);
        s = fmaf(df.y, df.y, s);
        s = fmaf(df.z, df.z, s);
        s = fmaf(df.w, df.w, s);
    }
    #pragma unroll
    for (int o = 32; o > 0; o >>= 1) s += __shfl_down(s, o, 64);
    __shared__ float ls[4];
    if ((threadIdx.x & 63) == 0) ls[threadIdx.x >> 6] = s;
    __syncthreads();
    if (threadIdx.x == 0) part[blockIdx.x] = ls[0] + ls[1] + ls[2] + ls[3];
}

// ---------------- K5: loss (from partials) + perplexity ---------------------
__global__ __launch_bounds__(256) void finalize(
    const float* __restrict__ counts, const float* __restrict__ part,
    float* __restrict__ out)
{
    __shared__ float sh[512];
    float h = 0.f;
    for (int k = threadIdx.x; k < K_CODES; k += 256) {
        float p = counts[k] * (1.0f / N_FLAT);
        h += p * logf(p + 1e-10f);
    }
    float s = 0.f;
    for (int i = threadIdx.x; i < 1024; i += 256) s += part[i];
    sh[threadIdx.x] = h;
    sh[256 + threadIdx.x] = s;
    __syncthreads();
    #pragma unroll
    for (int st = 128; st > 0; st >>= 1) {
        if (threadIdx.x < st) {
            sh[threadIdx.x] += sh[threadIdx.x + st];
            sh[256 + threadIdx.x] += sh[256 + threadIdx.x + st];
        }
        __syncthreads();
    }
    if (threadIdx.x == 0) {
        float perp = expf(-sh[0]);
        float loss = 1.25f * (sh[256] / 4194304.0f);
        if (isnan(loss) || isinf(loss)) loss = 0.1f;
        out[OFF_LOSS] = loss;
        out[OFF_PERP] = perp;
    }
}

extern "C" void kernel_launch(void* const* d_in, const int* in_sizes, int n_in,
                              void* d_out, int out_size, void* d_ws, size_t ws_size,
                              hipStream_t stream) {
    const float* x = (const float*)d_in[0];   // [32,128,32,32] fp32 NCHW
    const float* w = (const float*)d_in[1];   // [4096,128] fp32
    float* out = (float*)d_out;
    char* ws = (char*)d_ws;

    unsigned long long* packed = (unsigned long long*)(ws + WS_PACKED);
    float* counts = (float*)(ws + WS_COUNTS);
    float* wsq    = (float*)(ws + WS_WSQ);
    float* xsq    = (float*)(ws + WS_XSQ);
    float* part   = (float*)(ws + WS_PART);

    // init workspace (poisoned 0xAA before every launch)
    hipMemsetAsync(packed, 0xFF, (size_t)N_FLAT * 8, stream);        // u64 max
    hipMemsetAsync(counts, 0, (size_t)K_CODES * 4, stream);

    wsq_kernel<<<K_CODES, 64, 0, stream>>>(w, wsq);
    xsq_kernel<<<N_FLAT / 256, 256, 0, stream>>>(x, xsq);

    dim3 g2(256, 32);
    dist_argmin<<<g2, 256, 0, stream>>>(x, w, wsq, xsq, packed, out + OFF_ENC);

    combine<<<N_FLAT / 256, 256, 0, stream>>>(packed, out + OFF_IDX,
                                              out + OFF_ENC, counts);

    quantize_loss<<<1024, 256, 0, stream>>>(x, w, out + OFF_IDX,
                                            out + OFF_Q, part);

    finalize<<<1, 256, 0, stream>>>(counts, part, out);
}